// Round 1
// baseline (540.826 us; speedup 1.0000x reference)
//
#include <hip/hip_runtime.h>
#include <hip/hip_bf16.h>

// BinaryLinear: out = x @ sign(W)^T
// x: [32,4096,1024] f32  -> A [M=131072][K=1024]
// W: [1024,1024] f32     -> B^T = sign(W) [N=1024][K=1024] (already transposed layout!)
// out: [M][N] f32
//
// Strategy: pre-kernel converts sign(W) -> bf16 in d_ws (2 MiB, once).
// Main GEMM: bf16 MFMA 16x16x32, BM=128 x BN=256 x BK=32, 256 threads (4 waves 2x2),
// per-wave 64x128 (acc[4][8]). A reg-staged f32->bf16 into padded LDS (80B rows,
// conflict-free b128 reads). B staged via global_load_lds(16B) with chunk-XOR swizzle
// applied on the pre-swizzled global source (m173 pattern). Double-buffered, 2-barrier loop.

typedef __attribute__((ext_vector_type(8))) short bf16x8;
typedef __attribute__((ext_vector_type(4))) float f32x4;

#define BM 128
#define BN 256
#define BK 32
#define KDIM 1024
#define NDIM 1024
#define NKSTEP (KDIM / BK)
#define PADA 40  // ushorts per sA row: 32 data + 8 pad => 80-byte rows (conflict-free b128)

__device__ __forceinline__ unsigned short f2bf(float f) {
  union { float f; unsigned int u; } c; c.f = f;
  unsigned int u = c.u;
  // round-to-nearest-even truncation to bf16
  return (unsigned short)((u + 0x7fffu + ((u >> 16) & 1u)) >> 16);
}

// ---- pre-kernel: Bs[n][k] = sign(W[n][k]) as bf16 (+1, -1, or 0) ----
__global__ void sign_kernel(const float4* __restrict__ W, ushort4* __restrict__ Bs, int n4) {
  int i = blockIdx.x * blockDim.x + threadIdx.x;
  if (i >= n4) return;
  float4 v = W[i];
  const float* pv = (const float*)&v;
  ushort4 r;
  unsigned short* pr = (unsigned short*)&r;
#pragma unroll
  for (int j = 0; j < 4; ++j) {
    union { float f; unsigned int u; } c; c.f = pv[j];
    pr[j] = ((c.u & 0x7fffffffu) == 0u)
                ? (unsigned short)0
                : (unsigned short)(0x3f80u | ((c.u >> 16) & 0x8000u));
  }
  Bs[i] = r;
}

// ---- main GEMM ----
__global__ __launch_bounds__(256) void bgemm_kernel(
    const float* __restrict__ X,
    const unsigned short* __restrict__ Bs,
    float* __restrict__ O) {
  __shared__ unsigned short sA[2][BM * PADA];  // 2 x 10240 B
  __shared__ unsigned short sB[2][BN * BK];    // 2 x 16384 B  (total 53.25 KB)

  const int t = threadIdx.x;
  const int l = t & 63;
  const int w = t >> 6;   // wave 0..3
  const int wr = w >> 1;  // row-group 0..1 (64 rows each)
  const int wc = w & 1;   // col-group 0..1 (128 cols each)
  const int bm = blockIdx.x >> 2;  // N fastest: 4 N-tiles of same M adjacent -> LLC A reuse
  const int bn = blockIdx.x & 3;
  const size_t m0 = (size_t)bm * BM;
  const int N0 = bn * BN;

  // A staging: 128x32 f32 = 4096 elems, 16 per thread = 4x float4
  const float* ag[4];
  int aw[4];
#pragma unroll
  for (int s = 0; s < 4; ++s) {
    int idx = s * 256 + t;
    int r = idx >> 3;
    int c4 = (idx & 7) * 4;
    ag[s] = X + (m0 + (size_t)r) * KDIM + c4;
    aw[s] = r * PADA + c4;
  }

  // B staging: 256x32 bf16 = 1024 16B-chunks, 4 per thread.
  // LDS chunk c = n*4 + q holds global k-chunk kb = q ^ ((n>>1)&3)  (bank swizzle)
  const unsigned short* bg[4];
  int bw[4];
#pragma unroll
  for (int i = 0; i < 4; ++i) {
    int c = i * 256 + t;
    int n = c >> 2;
    int q = c & 3;
    int kb2 = q ^ ((n >> 1) & 3);
    bg[i] = Bs + (size_t)(N0 + n) * KDIM + kb2 * 8;
    bw[i] = c * 8;  // ushort index => byte offset c*16 (linear, matches gll dest rule)
  }

  // fragment read offsets
  const int ll = l & 15;
  const int kb = l >> 4;
  int offA[4], offB[8];
#pragma unroll
  for (int i = 0; i < 4; ++i)
    offA[i] = (wr * 64 + i * 16 + ll) * PADA + kb * 8;
#pragma unroll
  for (int j = 0; j < 8; ++j) {
    int n = wc * 128 + j * 16 + ll;
    int q = kb ^ ((n >> 1) & 3);
    offB[j] = n * BK + q * 8;
  }

  f32x4 acc[4][8];
#pragma unroll
  for (int i = 0; i < 4; ++i)
#pragma unroll
    for (int j = 0; j < 8; ++j) acc[i][j] = (f32x4)0.0f;

#define STAGE(buf, k0)                                                         \
  do {                                                                         \
    _Pragma("unroll") for (int i = 0; i < 4; ++i)                              \
        __builtin_amdgcn_global_load_lds(                                      \
            (const __attribute__((address_space(1))) void*)(bg[i] + (k0)),     \
            (__attribute__((address_space(3))) void*)(&sB[buf][bw[i]]),        \
            16, 0, 0);                                                         \
    _Pragma("unroll") for (int s = 0; s < 4; ++s) {                            \
      float4 v = *reinterpret_cast<const float4*>(ag[s] + (k0));               \
      ushort4 h;                                                               \
      h.x = f2bf(v.x); h.y = f2bf(v.y); h.z = f2bf(v.z); h.w = f2bf(v.w);      \
      *reinterpret_cast<ushort4*>(&sA[buf][aw[s]]) = h;                        \
    }                                                                          \
  } while (0)

  STAGE(0, 0);
  __syncthreads();

  for (int kk = 0; kk < NKSTEP; ++kk) {
    const int cur = kk & 1;
    if (kk + 1 < NKSTEP) {
      STAGE(cur ^ 1, (kk + 1) * BK);
    }
    const unsigned short* sa = sA[cur];
    const unsigned short* sb = sB[cur];
    bf16x8 av[4];
    bf16x8 bv[8];
#pragma unroll
    for (int i = 0; i < 4; ++i)
      av[i] = *reinterpret_cast<const bf16x8*>(sa + offA[i]);
#pragma unroll
    for (int j = 0; j < 8; ++j)
      bv[j] = *reinterpret_cast<const bf16x8*>(sb + offB[j]);
#pragma unroll
    for (int i = 0; i < 4; ++i)
#pragma unroll
      for (int j = 0; j < 8; ++j)
        acc[i][j] = __builtin_amdgcn_mfma_f32_16x16x32_bf16(av[i], bv[j], acc[i][j], 0, 0, 0);
    __syncthreads();
  }

  // epilogue: C/D layout col = lane&15, row = (lane>>4)*4 + reg
  const int crow = (l >> 4) * 4;
#pragma unroll
  for (int i = 0; i < 4; ++i) {
    const size_t r0 = m0 + wr * 64 + i * 16 + crow;
#pragma unroll
    for (int j = 0; j < 8; ++j) {
      const int col = N0 + wc * 128 + j * 16 + ll;
      float* op = O + r0 * NDIM + col;
#pragma unroll
      for (int e = 0; e < 4; ++e) op[(size_t)e * NDIM] = acc[i][j][e];
    }
  }
#undef STAGE
}

// ---- fallback (only if ws too small for the 2 MiB sign buffer) ----
__global__ void naive_kernel(const float* __restrict__ X, const float* __restrict__ W,
                             float* __restrict__ O, long long total) {
  long long idx = (long long)blockIdx.x * blockDim.x + threadIdx.x;
  if (idx >= total) return;
  int n = (int)(idx & (NDIM - 1));
  long long m = idx >> 10;
  const float* xr = X + m * KDIM;
  const float* wr = W + (long long)n * KDIM;
  float s = 0.f;
  for (int k = 0; k < KDIM; ++k) {
    float wv = wr[k];
    float sg = (wv > 0.f) ? 1.f : ((wv < 0.f) ? -1.f : 0.f);
    s += xr[k] * sg;
  }
  O[idx] = s;
}

extern "C" void kernel_launch(void* const* d_in, const int* in_sizes, int n_in,
                              void* d_out, int out_size, void* d_ws, size_t ws_size,
                              hipStream_t stream) {
  const float* X = (const float*)d_in[0];
  const float* W = (const float*)d_in[1];
  float* O = (float*)d_out;
  const long long M = (long long)in_sizes[0] / KDIM;  // 131072

  const size_t need_ws = (size_t)NDIM * KDIM * sizeof(unsigned short);  // 2 MiB
  if (ws_size >= need_ws && (M % BM) == 0) {
    unsigned short* Bs = (unsigned short*)d_ws;
    // 1) binarize weights once: 1M elems, float4-vectorized
    int n4 = (NDIM * KDIM) / 4;
    sign_kernel<<<dim3(n4 / 256), dim3(256), 0, stream>>>(
        (const float4*)W, (ushort4*)Bs, n4);
    // 2) MFMA GEMM: grid = (M/128) x (N/256), N fastest for LLC A-tile reuse
    dim3 grid((unsigned)((M / BM) * (NDIM / BN)));
    bgemm_kernel<<<grid, dim3(256), 0, stream>>>(X, Bs, O);
  } else {
    long long total = M * NDIM;
    long long blocks = (total + 255) / 256;
    naive_kernel<<<dim3((unsigned)blocks), dim3(256), 0, stream>>>(X, W, O, total);
  }
}

// Round 2
// 526.280 us; speedup vs baseline: 1.0276x; 1.0276x over previous
//
#include <hip/hip_runtime.h>
#include <hip/hip_bf16.h>

// BinaryLinear: out = x @ sign(W)^T
// x: [32,4096,1024] f32 -> A [M=131072][K=1024]
// W: [1024,1024] f32    -> B^T = sign(W) [N=1024][K=1024] bf16 in d_ws (once)
// out: [M][N] f32
//
// R2 changes vs R1 (580us, VALUBusy 43% > MfmaUtil 20%, FETCH 2.1x ideal):
//  - A f32->bf16 via v_cvt_pk_bf16_f32 (1 instr / 2 elems) instead of 5-op RNE twiddle
//  - A staging: thread owns 16 contiguous floats of one row -> 2x b128 LDS writes,
//    bank-group pattern is exact 2-way (free) on 80B-padded rows
//  - XCD-bijective block swizzle: 4 N-tile sharers of each A M-tile -> same XCD L2

typedef __attribute__((ext_vector_type(8))) short bf16x8;
typedef __attribute__((ext_vector_type(4))) float f32x4;

#define BM 128
#define BN 256
#define BK 32
#define KDIM 1024
#define NDIM 1024
#define NKSTEP (KDIM / BK)
#define PADA 40  // ushorts per sA row: 32 data + 8 pad => 80-byte rows

__device__ __forceinline__ unsigned cvt2(float a, float b) {
  unsigned r;
  // dst.lo = bf16(a), dst.hi = bf16(b)  (RNE)
  asm("v_cvt_pk_bf16_f32 %0, %1, %2" : "=v"(r) : "v"(a), "v"(b));
  return r;
}

// ---- pre-kernel: Bs[n][k] = sign(W[n][k]) as bf16 (+1, -1, or 0) ----
__global__ void sign_kernel(const float4* __restrict__ W, ushort4* __restrict__ Bs, int n4) {
  int i = blockIdx.x * blockDim.x + threadIdx.x;
  if (i >= n4) return;
  float4 v = W[i];
  const float* pv = (const float*)&v;
  ushort4 r;
  unsigned short* pr = (unsigned short*)&r;
#pragma unroll
  for (int j = 0; j < 4; ++j) {
    union { float f; unsigned int u; } c; c.f = pv[j];
    pr[j] = ((c.u & 0x7fffffffu) == 0u)
                ? (unsigned short)0
                : (unsigned short)(0x3f80u | ((c.u >> 16) & 0x8000u));
  }
  Bs[i] = r;
}

// ---- main GEMM ----
__global__ __launch_bounds__(256) void bgemm_kernel(
    const float* __restrict__ X,
    const unsigned short* __restrict__ Bs,
    float* __restrict__ O) {
  __shared__ unsigned short sA[2][BM * PADA];  // 2 x 10240 B
  __shared__ unsigned short sB[2][BN * BK];    // 2 x 16384 B  (53.25 KB -> 3 blocks/CU)

  const int t = threadIdx.x;
  const int l = t & 63;
  const int w = t >> 6;   // wave 0..3
  const int wr = w >> 1;  // row-group (64 rows)
  const int wc = w & 1;   // col-group (128 cols)

  // XCD-bijective swizzle (grid = 4096 = 8*512): 4 N-tiles of one M-tile land
  // adjacent on the SAME XCD -> A M-tile (512KB) served from that XCD's L2.
  const unsigned nwg = gridDim.x;
  unsigned swz = blockIdx.x;
  if ((nwg & 7u) == 0u) swz = (blockIdx.x & 7u) * (nwg >> 3) + (blockIdx.x >> 3);
  const int bm = (int)(swz >> 2);  // N fastest within swizzled order
  const int bn = (int)(swz & 3u);
  const size_t m0 = (size_t)bm * BM;
  const int N0 = bn * BN;

  // A staging: thread t owns row r = t>>1, k-half h = (t&1)*16 (16 contiguous floats)
  const int ar = t >> 1;
  const int ah = (t & 1) * 16;
  const float* ag = X + (m0 + (size_t)ar) * KDIM + ah;
  const int aw = ar * PADA + ah;  // ushort index in sA

  // B staging: 256x32 bf16 = 1024 16B-chunks, 4 per thread.
  // LDS chunk c = n*4 + q holds global k-chunk kb = q ^ ((n>>1)&3) (bank swizzle,
  // applied on the pre-swizzled global source; LDS dest stays linear per gll rule)
  const unsigned short* bg[4];
  int bw[4];
#pragma unroll
  for (int i = 0; i < 4; ++i) {
    int c = i * 256 + t;
    int n = c >> 2;
    int q = c & 3;
    int kb2 = q ^ ((n >> 1) & 3);
    bg[i] = Bs + (size_t)(N0 + n) * KDIM + kb2 * 8;
    bw[i] = c * 8;  // ushort index => byte offset c*16
  }

  // fragment read offsets
  const int ll = l & 15;
  const int kb = l >> 4;
  int offA[4], offB[8];
#pragma unroll
  for (int i = 0; i < 4; ++i)
    offA[i] = (wr * 64 + i * 16 + ll) * PADA + kb * 8;
#pragma unroll
  for (int j = 0; j < 8; ++j) {
    int n = wc * 128 + j * 16 + ll;
    int q = kb ^ ((n >> 1) & 3);
    offB[j] = n * BK + q * 8;
  }

  f32x4 acc[4][8];
#pragma unroll
  for (int i = 0; i < 4; ++i)
#pragma unroll
    for (int j = 0; j < 8; ++j) acc[i][j] = (f32x4)0.0f;

#define STAGE(buf, k0)                                                         \
  do {                                                                         \
    _Pragma("unroll") for (int i = 0; i < 4; ++i)                              \
        __builtin_amdgcn_global_load_lds(                                      \
            (const __attribute__((address_space(1))) void*)(bg[i] + (k0)),     \
            (__attribute__((address_space(3))) void*)(&sB[buf][bw[i]]),        \
            16, 0, 0);                                                         \
    const float4* ap = reinterpret_cast<const float4*>(ag + (k0));             \
    float4 v0 = ap[0], v1 = ap[1], v2 = ap[2], v3 = ap[3];                     \
    uint4 lo, hi;                                                              \
    lo.x = cvt2(v0.x, v0.y); lo.y = cvt2(v0.z, v0.w);                          \
    lo.z = cvt2(v1.x, v1.y); lo.w = cvt2(v1.z, v1.w);                          \
    hi.x = cvt2(v2.x, v2.y); hi.y = cvt2(v2.z, v2.w);                          \
    hi.z = cvt2(v3.x, v3.y); hi.w = cvt2(v3.z, v3.w);                          \
    *reinterpret_cast<uint4*>(&sA[buf][aw]) = lo;                              \
    *reinterpret_cast<uint4*>(&sA[buf][aw + 8]) = hi;                          \
  } while (0)

  STAGE(0, 0);
  __syncthreads();

  for (int kk = 0; kk < NKSTEP; ++kk) {
    const int cur = kk & 1;
    if (kk + 1 < NKSTEP) {
      STAGE(cur ^ 1, (kk + 1) * BK);
    }
    const unsigned short* sa = sA[cur];
    const unsigned short* sb = sB[cur];
    bf16x8 av[4];
    bf16x8 bv[8];
#pragma unroll
    for (int i = 0; i < 4; ++i)
      av[i] = *reinterpret_cast<const bf16x8*>(sa + offA[i]);
#pragma unroll
    for (int j = 0; j < 8; ++j)
      bv[j] = *reinterpret_cast<const bf16x8*>(sb + offB[j]);
#pragma unroll
    for (int i = 0; i < 4; ++i)
#pragma unroll
      for (int j = 0; j < 8; ++j)
        acc[i][j] = __builtin_amdgcn_mfma_f32_16x16x32_bf16(av[i], bv[j], acc[i][j], 0, 0, 0);
    __syncthreads();
  }

  // epilogue: C/D layout col = lane&15, row = (lane>>4)*4 + reg
  const int crow = (l >> 4) * 4;
#pragma unroll
  for (int i = 0; i < 4; ++i) {
    const size_t r0 = m0 + wr * 64 + i * 16 + crow;
#pragma unroll
    for (int j = 0; j < 8; ++j) {
      const int col = N0 + wc * 128 + j * 16 + ll;
      float* op = O + r0 * NDIM + col;
#pragma unroll
      for (int e = 0; e < 4; ++e) op[(size_t)e * NDIM] = acc[i][j][e];
    }
  }
#undef STAGE
}

// ---- fallback (only if ws too small for the 2 MiB sign buffer) ----
__global__ void naive_kernel(const float* __restrict__ X, const float* __restrict__ W,
                             float* __restrict__ O, long long total) {
  long long idx = (long long)blockIdx.x * blockDim.x + threadIdx.x;
  if (idx >= total) return;
  int n = (int)(idx & (NDIM - 1));
  long long m = idx >> 10;
  const float* xr = X + m * KDIM;
  const float* wr = W + (long long)n * KDIM;
  float s = 0.f;
  for (int k = 0; k < KDIM; ++k) {
    float wv = wr[k];
    float sg = (wv > 0.f) ? 1.f : ((wv < 0.f) ? -1.f : 0.f);
    s += xr[k] * sg;
  }
  O[idx] = s;
}

extern "C" void kernel_launch(void* const* d_in, const int* in_sizes, int n_in,
                              void* d_out, int out_size, void* d_ws, size_t ws_size,
                              hipStream_t stream) {
  const float* X = (const float*)d_in[0];
  const float* W = (const float*)d_in[1];
  float* O = (float*)d_out;
  const long long M = (long long)in_sizes[0] / KDIM;  // 131072

  const size_t need_ws = (size_t)NDIM * KDIM * sizeof(unsigned short);  // 2 MiB
  if (ws_size >= need_ws && (M % BM) == 0) {
    unsigned short* Bs = (unsigned short*)d_ws;
    int n4 = (NDIM * KDIM) / 4;
    sign_kernel<<<dim3(n4 / 256), dim3(256), 0, stream>>>(
        (const float4*)W, (ushort4*)Bs, n4);
    dim3 grid((unsigned)((M / BM) * (NDIM / BN)));
    bgemm_kernel<<<grid, dim3(256), 0, stream>>>(X, Bs, O);
  } else {
    long long total = M * NDIM;
    long long blocks = (total + 255) / 256;
    naive_kernel<<<dim3((unsigned)blocks), dim3(256), 0, stream>>>(X, W, O, total);
  }
}